// Round 18
// baseline (271.163 us; speedup 1.0000x reference)
//
#include <hip/hip_runtime.h>
#include <hip/hip_fp16.h>
#include <math.h>

#define N_ 50000
#define E_ 640000
#define H_ 128
#define L_ 3
#define G_ 256
#define C_ 10
#define NEG_SLOPE 0.2f

#define ABLK ((N_ + 3) / 4)          // 12500 (4 nodes per block)
#define MAXDEG 64
#define GEMM_BLKS ((N_ + 63) / 64)   // 782
#define FILL_T (GEMM_BLKS * 256)     // 200192 fill threads (4 edges each)

typedef _Float16 half8 __attribute__((ext_vector_type(8)));
typedef float f32x4 __attribute__((ext_vector_type(4)));

__device__ __forceinline__ float leaky(float x) { return x > 0.f ? x : NEG_SLOPE * x; }
// output position p holds feature pi_out(p); same for every layer's h16
__device__ __forceinline__ int pi_out(int p) { return ((p & 7) << 4) + (p >> 3); }

// ---------------- weight prep for one layer (256 threads) ----------------
__device__ __forceinline__ void prep_layer(int l, const float* __restrict__ Wc,
                                           const float* __restrict__ a_src,
                                           const float* __restrict__ a_dst,
                                           const float* __restrict__ bc,
                                           __half* __restrict__ Wt,
                                           float* __restrict__ bcp) {
    const float* W = Wc + l * 16384;
    __half* T = Wt + (size_t)l * 144 * 128;
    int t = threadIdx.x;
    for (int e = t; e < 16384; e += 256) {
        int n = e >> 7, p = e & 127;
        int ks = (l == 0) ? p : pi_out(p);
        T[n * 128 + p] = __float2half(W[ks * 128 + n]);
    }
    if (t < 128) {
        int p = t;
        int ks = (l == 0) ? p : pi_out(p);
        const float* as = a_src + l * 128;
        const float* ad = a_dst + l * 128;
        float s = 0.f, d = 0.f;
#pragma unroll 8
        for (int n = 0; n < 128; n++) {
            float w = W[ks * 128 + n];
            s += w * as[n];
            d += w * ad[n];
        }
        T[128 * 128 + p] = __float2half(s);
        T[129 * 128 + p] = __float2half(d);
        bcp[l * 128 + p] = bc[l * 128 + pi_out(p)];
    } else {
        int kk = t - 128;
        for (int r = 130; r < 144; r++) T[r * 128 + kk] = __float2half(0.f);
    }
}

// ---------------- kernel 1: prep all 3 layers (blocks 0..2) + zero cursors ----------------
__global__ __launch_bounds__(256) void zero_prep(int* __restrict__ cur,
                                                 const float* __restrict__ Wc,
                                                 const float* __restrict__ a_src,
                                                 const float* __restrict__ a_dst,
                                                 const float* __restrict__ bc,
                                                 __half* __restrict__ Wt,
                                                 float* __restrict__ bcp) {
    if (blockIdx.x < L_) {
        prep_layer(blockIdx.x, Wc, a_src, a_dst, bc, Wt, bcp);
    } else {
        int i = (blockIdx.x - L_) * 256 + threadIdx.x;
        if (i < N_) cur[i] = 0;
    }
}

// ---------------- kernel 2: GEMM layer-0 (A-direct) with embedded slot-fill ----------------
__global__ __launch_bounds__(256) void gemm0_fill(const float* __restrict__ A,
                                                  const __half* __restrict__ Wt,
                                                  __half* __restrict__ h16,
                                                  float* __restrict__ es,
                                                  float* __restrict__ ed,
                                                  const int* __restrict__ src,
                                                  const int* __restrict__ dst,
                                                  int* __restrict__ cur,
                                                  int* __restrict__ col_slots) {
    __shared__ __half Bsw[144 * 128];   // 36 KB
    int tid = threadIdx.x;
    int brow = blockIdx.x * 64;
    int w = tid >> 6, l = tid & 63;
    int lrow = l & 15, lk = l >> 4;

    // ---- edge loads (coalesced) ----
    int g = blockIdx.x * 256 + tid;
    int e1 = g + FILL_T, e2 = g + 2 * FILL_T, e3 = g + 3 * FILL_T;
    bool v3 = e3 < E_;
    int d0 = dst[g], d1 = dst[e1], d2 = dst[e2];
    int s0 = src[g], s1 = src[e1], s2 = src[e2];
    int d3 = 0, s3 = 0;
    if (v3) { d3 = dst[e3]; s3 = src[e3]; }

    // ---- atomics issued now; results consumed after the epilogue ----
    int p0 = atomicAdd(&cur[d0], 1);
    int p1 = atomicAdd(&cur[d1], 1);
    int p2 = atomicAdd(&cur[d2], 1);
    int p3 = MAXDEG;
    if (v3) p3 = atomicAdd(&cur[d3], 1);

    // ---- A-direct loads (fp32, this lane's MFMA fragment columns) ----
    int arow = brow + w * 16 + lrow;
    float4 av[8];
    if (arow < N_) {
        const float4* rp = (const float4*)(A + (size_t)arow * 128);
#pragma unroll
        for (int kk = 0; kk < 4; kk++) {
            av[2 * kk]     = rp[kk * 8 + lk * 2];
            av[2 * kk + 1] = rp[kk * 8 + lk * 2 + 1];
        }
    } else {
        float4 zz = make_float4(0.f, 0.f, 0.f, 0.f);
#pragma unroll
        for (int s = 0; s < 8; s++) av[s] = zz;
    }

    // ---- stage B: linear fp16 copy, swizzled (2304 16B chunks) ----
    {
        const float4* srcW = (const float4*)Wt;
#pragma unroll
        for (int i = 0; i < 9; i++) {
            int c = tid + i * 256;
            int o = c * 16;
            int n = o >> 8;
            float4 val = srcW[c];
            int addr = n * 256 + ((o & 255) ^ ((n & 7) << 4));
            *(float4*)((char*)Bsw + addr) = val;
        }
    }
    __syncthreads();

    // ---- convert A frags, MFMA: 9 n-tiles, 4 k-steps ----
    f32x4 acc[9];
#pragma unroll
    for (int t = 0; t < 9; t++) acc[t] = (f32x4)0.f;
#pragma unroll
    for (int kk = 0; kk < 4; kk++) {
        half8 af;
        float4 a0 = av[2 * kk], a1 = av[2 * kk + 1];
        af[0] = (_Float16)a0.x; af[1] = (_Float16)a0.y; af[2] = (_Float16)a0.z; af[3] = (_Float16)a0.w;
        af[4] = (_Float16)a1.x; af[5] = (_Float16)a1.y; af[6] = (_Float16)a1.z; af[7] = (_Float16)a1.w;
        int kbyte = kk * 64 + lk * 16;
#pragma unroll
        for (int t = 0; t < 9; t++) {
            int n = t * 16 + lrow;
            half8 bf = *(const half8*)((const char*)Bsw + n * 256 + (kbyte ^ ((n & 7) << 4)));
            acc[t] = __builtin_amdgcn_mfma_f32_16x16x32_f16(af, bf, acc[t], 0, 0, 0);
        }
    }

    // ---- epilogue: row=(lk*4+r), lane's 8 cols stored contiguously ----
    int row0 = brow + w * 16 + lk * 4;
#pragma unroll
    for (int rr = 0; rr < 4; rr++) {
        int gr = row0 + rr;
        if (gr < N_) {
            half8 hv;
#pragma unroll
            for (int t = 0; t < 8; t++) hv[t] = (_Float16)acc[t][rr];
            *(half8*)(h16 + (size_t)gr * 128 + lrow * 8) = hv;
            if (lrow == 0) es[gr] = acc[8][rr];
            else if (lrow == 1) ed[gr] = acc[8][rr];
        }
    }

    // ---- slot stores (atomic results completed under the MFMA body) ----
    if (p0 < MAXDEG) col_slots[d0 * MAXDEG + p0] = s0;
    if (p1 < MAXDEG) col_slots[d1 * MAXDEG + p1] = s1;
    if (p2 < MAXDEG) col_slots[d2 * MAXDEG + p2] = s2;
    if (p3 < MAXDEG) col_slots[d3 * MAXDEG + p3] = s3;
}

// ---------------- fused aggregate -> GEMM (interior layers) ----------------
// Block = 64 nodes. Stage B; each wave aggregates 16 nodes (shfl-broadcast edges,
// 4 unconditional flat batches = 16 gathers in flight; overshoot hits self row with
// zero weight), writes ReLU'd h rows into the swizzled Asw tile; one sync; then the
// staged-A MFMA produces the next layer's g (+ fused es/ed). h never hits global.
__global__ __launch_bounds__(256) void agg_gemm(const __half* __restrict__ gin,
                                                const float* __restrict__ es_in,
                                                const float* __restrict__ ed_in,
                                                const int* __restrict__ cur,
                                                const int* __restrict__ col_slots,
                                                const float* __restrict__ biasp,
                                                const __half* __restrict__ Wt_l,
                                                __half* __restrict__ gout,
                                                float* __restrict__ es_out,
                                                float* __restrict__ ed_out) {
    __shared__ __half Asw[64 * 128];    // 16 KB
    __shared__ __half Bsw[144 * 128];   // 36 KB
    int tid = threadIdx.x;
    int brow = blockIdx.x * 64;
    int w = tid >> 6, lane = tid & 63;
    int eg = lane >> 4, fl = lane & 15;

    // ---- stage B (independent of the aggregate phase) ----
    {
        const float4* srcW = (const float4*)Wt_l;
#pragma unroll
        for (int i = 0; i < 9; i++) {
            int c = tid + i * 256;
            int o = c * 16;
            int n = o >> 8;
            float4 val = srcW[c];
            int addr = n * 256 + ((o & 255) ^ ((n & 7) << 4));
            *(float4*)((char*)Bsw + addr) = val;
        }
    }

    // ---- aggregate: wave w handles nodes w*16 .. w*16+15 ----
    for (int nt = 0; nt < 16; ++nt) {
        int nl = w * 16 + nt;
        int node = brow + nl;
        int wr_addr = nl * 256 + ((fl * 16) ^ ((nl & 7) << 4));
        if (node >= N_) {
            if (eg == 0) *(float4*)((char*)Asw + wr_addr) = make_float4(0.f, 0.f, 0.f, 0.f);
            continue;
        }
        int deg = min(cur[node], MAXDEG);
        int craw = col_slots[node * MAXDEG + lane];
        float edn = ed_in[node];
        float es_self = es_in[node];
        int c0 = (lane < deg) ? min(max(craw, 0), N_ - 1) : node;  // overshoot -> self
        float w0 = 0.f;
        if (lane < deg) w0 = __expf(fminf(leaky(es_in[c0] + edn), 30.f));
        float zl = w0;

        float acc[8] = {0.f, 0.f, 0.f, 0.f, 0.f, 0.f, 0.f, 0.f};
#pragma unroll
        for (int b = 0; b < 4; ++b) {     // unconditional flat batches cover slots 0..63
            int jb = eg + (b << 4);
            int s0 = __shfl(c0, jb);
            int s1 = __shfl(c0, jb + 4);
            int s2 = __shfl(c0, jb + 8);
            int s3 = __shfl(c0, jb + 12);
            float a0 = __shfl(w0, jb);
            float a1 = __shfl(w0, jb + 4);
            float a2 = __shfl(w0, jb + 8);
            float a3 = __shfl(w0, jb + 12);
            union { float4 f4; __half2 h2[4]; } u0, u1, u2, u3;
            u0.f4 = *(const float4*)(gin + (size_t)s0 * 128 + fl * 8);
            u1.f4 = *(const float4*)(gin + (size_t)s1 * 128 + fl * 8);
            u2.f4 = *(const float4*)(gin + (size_t)s2 * 128 + fl * 8);
            u3.f4 = *(const float4*)(gin + (size_t)s3 * 128 + fl * 8);
#pragma unroll
            for (int qq = 0; qq < 4; qq++) {
                float2 f0 = __half22float2(u0.h2[qq]);
                float2 f1 = __half22float2(u1.h2[qq]);
                float2 f2 = __half22float2(u2.h2[qq]);
                float2 f3 = __half22float2(u3.h2[qq]);
                acc[2 * qq]     += a0 * f0.x + a1 * f1.x + a2 * f2.x + a3 * f3.x;
                acc[2 * qq + 1] += a0 * f0.y + a1 * f1.y + a2 * f2.y + a3 * f3.y;
            }
        }
        // fold edge groups, then z
#pragma unroll
        for (int qq = 0; qq < 8; qq++) {
            acc[qq] += __shfl_xor(acc[qq], 16);
            acc[qq] += __shfl_xor(acc[qq], 32);
        }
#pragma unroll
        for (int o = 32; o; o >>= 1) zl += __shfl_xor(zl, o);
        float ws = __expf(fminf(leaky(es_self + edn), 30.f));
        float inv = 1.0f / (zl + ws + 1e-16f);

        if (eg == 0) {
            union { float4 f4; __half2 h2[4]; } su;
            su.f4 = *(const float4*)(gin + (size_t)node * 128 + fl * 8);
            const float4* bp = (const float4*)(biasp + fl * 8);
            float4 b0 = bp[0], b1 = bp[1];
            float bq[8] = {b0.x, b0.y, b0.z, b0.w, b1.x, b1.y, b1.z, b1.w};
            union { float4 f4; __half2 h2[4]; } ou;
#pragma unroll
            for (int qq = 0; qq < 4; qq++) {
                float2 sv = __half22float2(su.h2[qq]);
                float v0 = fmaxf((acc[2 * qq]     + ws * sv.x) * inv + bq[2 * qq],     0.f);
                float v1 = fmaxf((acc[2 * qq + 1] + ws * sv.y) * inv + bq[2 * qq + 1], 0.f);
                ou.h2[qq] = __floats2half2_rn(v0, v1);
            }
            *(float4*)((char*)Asw + wr_addr) = ou.f4;
        }
    }
    __syncthreads();

    // ---- MFMA: staged-A path, 9 n-tiles, 4 k-steps ----
    int lrow = lane & 15, lk = lane >> 4;
    f32x4 acc2[9];
#pragma unroll
    for (int t = 0; t < 9; t++) acc2[t] = (f32x4)0.f;
#pragma unroll
    for (int kk = 0; kk < 4; kk++) {
        int kbyte = kk * 64 + lk * 16;
        int ar = w * 16 + lrow;
        half8 af = *(const half8*)((const char*)Asw + ar * 256 + (kbyte ^ ((ar & 7) << 4)));
#pragma unroll
        for (int t = 0; t < 9; t++) {
            int n = t * 16 + lrow;
            half8 bf = *(const half8*)((const char*)Bsw + n * 256 + (kbyte ^ ((n & 7) << 4)));
            acc2[t] = __builtin_amdgcn_mfma_f32_16x16x32_f16(af, bf, acc2[t], 0, 0, 0);
        }
    }

    // ---- epilogue ----
    int row0 = brow + w * 16 + lk * 4;
#pragma unroll
    for (int rr = 0; rr < 4; rr++) {
        int gr = row0 + rr;
        if (gr < N_) {
            half8 hv;
#pragma unroll
            for (int t = 0; t < 8; t++) hv[t] = (_Float16)acc2[t][rr];
            *(half8*)(gout + (size_t)gr * 128 + lrow * 8) = hv;
            if (lrow == 0) es_out[gr] = acc2[8][rr];
            else if (lrow == 1) ed_out[gr] = acc2[8][rr];
        }
    }
}

// ---------------- final edge-softmax + gather-aggregate (one wave per dst node) ----------------
__global__ __launch_bounds__(256) void gat_aggregate(const __half* __restrict__ h16,
                                                     const float* __restrict__ es,
                                                     const float* __restrict__ ed,
                                                     const int* __restrict__ cur,
                                                     const int* __restrict__ col_slots,
                                                     const float* __restrict__ biasp,
                                                     __half* __restrict__ hout) {
    __shared__ int   lds_s[4][64];
    __shared__ float lds_w[4][64];
    int wv = threadIdx.x >> 6;
    int lane = threadIdx.x & 63;
    int node = blockIdx.x * 4 + wv;
    if (node >= N_) return;

    int deg_raw = cur[node];
    int craw = col_slots[node * MAXDEG + lane];
    float edn = ed[node];
    float es_self = es[node];

    int deg = min(deg_raw, MAXDEG);
    int c0 = (lane < deg) ? min(max(craw, 0), N_ - 1) : node;
    lds_s[wv][lane] = c0;

    float w0 = 0.f;
    if (lane < deg) w0 = __expf(fminf(leaky(es[c0] + edn), 30.f));
    float zl = w0;
    lds_w[wv][lane] = w0;

    int eg = lane >> 4;
    int fl = lane & 15;

    float acc[8] = {0.f, 0.f, 0.f, 0.f, 0.f, 0.f, 0.f, 0.f};
    int K4 = (deg + 15) >> 4;
    for (int b = 0; b < K4; ++b) {
        int jb = eg + (b << 4);
        int s0 = lds_s[wv][jb];
        int s1 = lds_s[wv][jb + 4];
        int s2 = lds_s[wv][jb + 8];
        int s3 = lds_s[wv][jb + 12];
        float a0 = lds_w[wv][jb];
        float a1 = lds_w[wv][jb + 4];
        float a2 = lds_w[wv][jb + 8];
        float a3 = lds_w[wv][jb + 12];
        union { float4 f4; __half2 h2[4]; } u0, u1, u2, u3;
        u0.f4 = *(const float4*)(h16 + (size_t)s0 * 128 + fl * 8);
        u1.f4 = *(const float4*)(h16 + (size_t)s1 * 128 + fl * 8);
        u2.f4 = *(const float4*)(h16 + (size_t)s2 * 128 + fl * 8);
        u3.f4 = *(const float4*)(h16 + (size_t)s3 * 128 + fl * 8);
#pragma unroll
        for (int qq = 0; qq < 4; qq++) {
            float2 f0 = __half22float2(u0.h2[qq]);
            float2 f1 = __half22float2(u1.h2[qq]);
            float2 f2 = __half22float2(u2.h2[qq]);
            float2 f3 = __half22float2(u3.h2[qq]);
            acc[2 * qq]     += a0 * f0.x + a1 * f1.x + a2 * f2.x + a3 * f3.x;
            acc[2 * qq + 1] += a0 * f0.y + a1 * f1.y + a2 * f2.y + a3 * f3.y;
        }
    }

#pragma unroll
    for (int qq = 0; qq < 8; qq++) {
        acc[qq] += __shfl_xor(acc[qq], 16);
        acc[qq] += __shfl_xor(acc[qq], 32);
    }
#pragma unroll
    for (int o = 32; o; o >>= 1) zl += __shfl_xor(zl, o);
    float ws = __expf(fminf(leaky(es_self + edn), 30.f));
    float inv = 1.0f / (zl + ws + 1e-16f);

    if (eg == 0) {
        union { float4 f4; __half2 h2[4]; } su;
        su.f4 = *(const float4*)(h16 + (size_t)node * 128 + fl * 8);
        const float4* bp = (const float4*)(biasp + fl * 8);
        float4 b0 = bp[0], b1 = bp[1];
        float bq[8] = {b0.x, b0.y, b0.z, b0.w, b1.x, b1.y, b1.z, b1.w};
        union { float4 f4; __half2 h2[4]; } ou;
#pragma unroll
        for (int qq = 0; qq < 4; qq++) {
            float2 sv = __half22float2(su.h2[qq]);
            float v0 = fmaxf((acc[2 * qq]     + ws * sv.x) * inv + bq[2 * qq],     0.f);
            float v1 = fmaxf((acc[2 * qq + 1] + ws * sv.y) * inv + bq[2 * qq + 1], 0.f);
            ou.h2[qq] = __floats2half2_rn(v0, v1);
        }
        *(float4*)(hout + (size_t)node * 128 + fl * 8) = ou.f4;
    }
}

// ---------------- fused global max pool + MLP head + log_softmax ----------------
__device__ __forceinline__ int lower_bound_batch(const int* __restrict__ batch, int val) {
    int lo = 0, hi = N_;
    while (lo < hi) {
        int mid = (lo + hi) >> 1;
        if (batch[mid] < val) lo = mid + 1;
        else hi = mid;
    }
    return lo;
}

__global__ __launch_bounds__(512) void pool_head(const __half* __restrict__ h16,
                                                 const int* __restrict__ batch,
                                                 const float* __restrict__ W1,
                                                 const float* __restrict__ b1,
                                                 const float* __restrict__ W2,
                                                 const float* __restrict__ b2,
                                                 float* __restrict__ out) {
    int g = blockIdx.x;
    int t = threadIdx.x;
    __shared__ float red[8][128];
    __shared__ float gs[128], gp[128], lg[C_], lse;

    int s = lower_bound_batch(batch, g);
    int e = lower_bound_batch(batch, g + 1);
    int fs = t & 15;
    int rg = t >> 4;
    float m[8] = {0.f, 0.f, 0.f, 0.f, 0.f, 0.f, 0.f, 0.f};
    for (int i = s + rg; i < e; i += 32) {
        union { float4 f4; __half2 h2[4]; } u;
        u.f4 = *(const float4*)(h16 + (size_t)i * 128 + fs * 8);
#pragma unroll
        for (int qq = 0; qq < 4; qq++) {
            float2 fv = __half22float2(u.h2[qq]);
            m[2 * qq]     = fmaxf(m[2 * qq],     fv.x);
            m[2 * qq + 1] = fmaxf(m[2 * qq + 1], fv.y);
        }
    }
#pragma unroll
    for (int qq = 0; qq < 8; qq++) {
        m[qq] = fmaxf(m[qq], __shfl_xor(m[qq], 16));
        m[qq] = fmaxf(m[qq], __shfl_xor(m[qq], 32));
    }
    int wid = t >> 6;
    if ((t & 48) == 0) {
#pragma unroll
        for (int qq = 0; qq < 8; qq++) red[wid][fs * 8 + qq] = m[qq];
    }
    __syncthreads();
    if (t < 128) {
        float mm = red[0][t];
#pragma unroll
        for (int w = 1; w < 8; w++) mm = fmaxf(mm, red[w][t]);
        gs[t] = mm;
    }
    __syncthreads();

    if (t < 128) {
        float acc = b1[t];
#pragma unroll 8
        for (int k = 0; k < 128; k++) {
            int f = pi_out(k);
            acc += gs[k] * W1[f * 128 + t];
        }
        gp[t] = fmaxf(acc, 0.f);
    }
    __syncthreads();
    if (t < C_) {
        float a2 = b2[t];
#pragma unroll 8
        for (int k = 0; k < 128; k++) a2 += gp[k] * W2[k * C_ + t];
        lg[t] = a2;
    }
    __syncthreads();
    if (t == 0) {
        float mm = lg[0];
#pragma unroll
        for (int i = 1; i < C_; i++) mm = fmaxf(mm, lg[i]);
        float ss = 0.f;
#pragma unroll
        for (int i = 0; i < C_; i++) ss += expf(lg[i] - mm);
        lse = mm + logf(ss);
    }
    __syncthreads();
    if (t < C_) out[g * C_ + t] = lg[t] - lse;
}

// ---------------- launch ----------------
extern "C" void kernel_launch(void* const* d_in, const int* in_sizes, int n_in,
                              void* d_out, int out_size, void* d_ws, size_t ws_size,
                              hipStream_t stream) {
    const float* x     = (const float*)d_in[0];
    const int*   eidx  = (const int*)d_in[1];
    const int*   batch = (const int*)d_in[2];
    const float* Wc    = (const float*)d_in[3];
    const float* a_src = (const float*)d_in[4];
    const float* a_dst = (const float*)d_in[5];
    const float* bc    = (const float*)d_in[6];
    const float* W1    = (const float*)d_in[7];
    const float* b1    = (const float*)d_in[8];
    const float* W2    = (const float*)d_in[9];
    const float* b2    = (const float*)d_in[10];
    float* out = (float*)d_out;

    const int* srcs = eidx;        // edge_index[0]
    const int* dsts = eidx + E_;   // edge_index[1]

    // workspace layout (16B-aligned segments)
    __half* hA    = (__half*)d_ws;                      // [N][128]
    __half* hB    = hA + (size_t)N_ * 128;              // [N][128]
    float*  esA   = (float*)(hB + (size_t)N_ * 128);    // N
    float*  edA   = esA + N_;                           // N
    float*  esB   = edA + N_;                           // N
    float*  edB   = esB + N_;                           // N
    float*  bcp   = edB + N_;                           // 3*128
    __half* Wt    = (__half*)(bcp + 3 * 128);           // 3*144*128
    int*    cur       = (int*)(Wt + (size_t)3 * 144 * 128); // N
    int*    col_slots = cur + N_;                           // MAXDEG*N

    // ---- kernel 1: prep all weights + zero cursors ----
    zero_prep<<<L_ + (N_ + 255) / 256, 256, 0, stream>>>(cur, Wc, a_src, a_dst, bc, Wt, bcp);

    // ---- kernel 2: GEMM layer 0 (A-direct) with embedded slot-fill -> g0 ----
    gemm0_fill<<<GEMM_BLKS, 256, 0, stream>>>(x, Wt, hA, esA, edA,
                                              srcs, dsts, cur, col_slots);

    // ---- fused aggregate+GEMM: layer 1 (g0 -> g1), layer 2 (g1 -> g2) ----
    agg_gemm<<<GEMM_BLKS, 256, 0, stream>>>(hA, esA, edA, cur, col_slots,
                                            bcp, Wt + (size_t)1 * 144 * 128,
                                            hB, esB, edB);
    agg_gemm<<<GEMM_BLKS, 256, 0, stream>>>(hB, esB, edB, cur, col_slots,
                                            bcp + 128, Wt + (size_t)2 * 144 * 128,
                                            hA, esA, edA);

    // ---- final aggregate (g2 -> h2) ----
    gat_aggregate<<<ABLK, 256, 0, stream>>>(hA, esA, edA, cur, col_slots,
                                            bcp + 256, hB);

    // ---- fused pool + head ----
    pool_head<<<G_, 512, 0, stream>>>(hB, batch, W1, b1, W2, b2, out);
}

// Round 19
// 185.912 us; speedup vs baseline: 1.4586x; 1.4586x over previous
//
#include <hip/hip_runtime.h>
#include <hip/hip_fp16.h>
#include <math.h>

#define N_ 50000
#define E_ 640000
#define H_ 128
#define L_ 3
#define G_ 256
#define C_ 10
#define NEG_SLOPE 0.2f

#define ABLK ((N_ + 3) / 4)          // 12500 (4 nodes per block)
#define MAXDEG 64
#define GEMM_BLKS ((N_ + 63) / 64)   // 782
#define FILL_T (GEMM_BLKS * 256)     // 200192 fill threads (4 edges each)

typedef _Float16 half8 __attribute__((ext_vector_type(8)));
typedef float f32x4 __attribute__((ext_vector_type(4)));

__device__ __forceinline__ float leaky(float x) { return x > 0.f ? x : NEG_SLOPE * x; }
// output position p holds feature pi_out(p); same for every layer's h16
__device__ __forceinline__ int pi_out(int p) { return ((p & 7) << 4) + (p >> 3); }

// ---------------- weight prep for one layer (256 threads) ----------------
__device__ __forceinline__ void prep_layer(int l, const float* __restrict__ Wc,
                                           const float* __restrict__ a_src,
                                           const float* __restrict__ a_dst,
                                           const float* __restrict__ bc,
                                           __half* __restrict__ Wt,
                                           float* __restrict__ bcp) {
    const float* W = Wc + l * 16384;
    __half* T = Wt + (size_t)l * 144 * 128;
    int t = threadIdx.x;
    for (int e = t; e < 16384; e += 256) {
        int n = e >> 7, p = e & 127;
        int ks = (l == 0) ? p : pi_out(p);
        T[n * 128 + p] = __float2half(W[ks * 128 + n]);
    }
    if (t < 128) {
        int p = t;
        int ks = (l == 0) ? p : pi_out(p);
        const float* as = a_src + l * 128;
        const float* ad = a_dst + l * 128;
        float s = 0.f, d = 0.f;
#pragma unroll 8
        for (int n = 0; n < 128; n++) {
            float w = W[ks * 128 + n];
            s += w * as[n];
            d += w * ad[n];
        }
        T[128 * 128 + p] = __float2half(s);
        T[129 * 128 + p] = __float2half(d);
        bcp[l * 128 + p] = bc[l * 128 + pi_out(p)];
    } else {
        int kk = t - 128;
        for (int r = 130; r < 144; r++) T[r * 128 + kk] = __float2half(0.f);
    }
}

// ---------------- kernel 1: prep all 3 layers (blocks 0..2) + zero cursors ----------------
__global__ __launch_bounds__(256) void zero_prep(int* __restrict__ cur,
                                                 const float* __restrict__ Wc,
                                                 const float* __restrict__ a_src,
                                                 const float* __restrict__ a_dst,
                                                 const float* __restrict__ bc,
                                                 __half* __restrict__ Wt,
                                                 float* __restrict__ bcp) {
    if (blockIdx.x < L_) {
        prep_layer(blockIdx.x, Wc, a_src, a_dst, bc, Wt, bcp);
    } else {
        int i = (blockIdx.x - L_) * 256 + threadIdx.x;
        if (i < N_) cur[i] = 0;
    }
}

// ---------------- kernel 2: GEMM layer-0 (A-direct) with embedded slot-fill ----------------
// A fragments loaded straight to registers (fp32, converted after sync); only B in
// LDS (36 KB). Atomics issued early, consumed after the epilogue.
__global__ __launch_bounds__(256) void gemm0_fill(const float* __restrict__ A,
                                                  const __half* __restrict__ Wt,
                                                  __half* __restrict__ h16,
                                                  float* __restrict__ es,
                                                  float* __restrict__ ed,
                                                  const int* __restrict__ src,
                                                  const int* __restrict__ dst,
                                                  int* __restrict__ cur,
                                                  int* __restrict__ col_slots) {
    __shared__ __half Bsw[144 * 128];   // 36 KB
    int tid = threadIdx.x;
    int brow = blockIdx.x * 64;
    int w = tid >> 6, l = tid & 63;
    int lrow = l & 15, lk = l >> 4;

    // ---- edge loads (coalesced) ----
    int g = blockIdx.x * 256 + tid;
    int e1 = g + FILL_T, e2 = g + 2 * FILL_T, e3 = g + 3 * FILL_T;
    bool v3 = e3 < E_;
    int d0 = dst[g], d1 = dst[e1], d2 = dst[e2];
    int s0 = src[g], s1 = src[e1], s2 = src[e2];
    int d3 = 0, s3 = 0;
    if (v3) { d3 = dst[e3]; s3 = src[e3]; }

    // ---- atomics issued now; results consumed after the epilogue ----
    int p0 = atomicAdd(&cur[d0], 1);
    int p1 = atomicAdd(&cur[d1], 1);
    int p2 = atomicAdd(&cur[d2], 1);
    int p3 = MAXDEG;
    if (v3) p3 = atomicAdd(&cur[d3], 1);

    // ---- A-direct loads (fp32, this lane's MFMA fragment columns) ----
    int arow = brow + w * 16 + lrow;
    float4 av[8];
    if (arow < N_) {
        const float4* rp = (const float4*)(A + (size_t)arow * 128);
#pragma unroll
        for (int kk = 0; kk < 4; kk++) {
            av[2 * kk]     = rp[kk * 8 + lk * 2];
            av[2 * kk + 1] = rp[kk * 8 + lk * 2 + 1];
        }
    } else {
        float4 zz = make_float4(0.f, 0.f, 0.f, 0.f);
#pragma unroll
        for (int s = 0; s < 8; s++) av[s] = zz;
    }

    // ---- stage B: linear fp16 copy, swizzled (2304 16B chunks) ----
    {
        const float4* srcW = (const float4*)Wt;
#pragma unroll
        for (int i = 0; i < 9; i++) {
            int c = tid + i * 256;
            int o = c * 16;
            int n = o >> 8;
            float4 val = srcW[c];
            int addr = n * 256 + ((o & 255) ^ ((n & 7) << 4));
            *(float4*)((char*)Bsw + addr) = val;
        }
    }
    __syncthreads();

    // ---- convert A frags, MFMA: 9 n-tiles, 4 k-steps ----
    f32x4 acc[9];
#pragma unroll
    for (int t = 0; t < 9; t++) acc[t] = (f32x4)0.f;
#pragma unroll
    for (int kk = 0; kk < 4; kk++) {
        half8 af;
        float4 a0 = av[2 * kk], a1 = av[2 * kk + 1];
        af[0] = (_Float16)a0.x; af[1] = (_Float16)a0.y; af[2] = (_Float16)a0.z; af[3] = (_Float16)a0.w;
        af[4] = (_Float16)a1.x; af[5] = (_Float16)a1.y; af[6] = (_Float16)a1.z; af[7] = (_Float16)a1.w;
        int kbyte = kk * 64 + lk * 16;
#pragma unroll
        for (int t = 0; t < 9; t++) {
            int n = t * 16 + lrow;
            half8 bf = *(const half8*)((const char*)Bsw + n * 256 + (kbyte ^ ((n & 7) << 4)));
            acc[t] = __builtin_amdgcn_mfma_f32_16x16x32_f16(af, bf, acc[t], 0, 0, 0);
        }
    }

    // ---- epilogue: row=(lk*4+r), lane's 8 cols stored contiguously ----
    int row0 = brow + w * 16 + lk * 4;
#pragma unroll
    for (int rr = 0; rr < 4; rr++) {
        int gr = row0 + rr;
        if (gr < N_) {
            half8 hv;
#pragma unroll
            for (int t = 0; t < 8; t++) hv[t] = (_Float16)acc[t][rr];
            *(half8*)(h16 + (size_t)gr * 128 + lrow * 8) = hv;
            if (lrow == 0) es[gr] = acc[8][rr];
            else if (lrow == 1) ed[gr] = acc[8][rr];
        }
    }

    // ---- slot stores (atomic results completed under the MFMA body) ----
    if (p0 < MAXDEG) col_slots[d0 * MAXDEG + p0] = s0;
    if (p1 < MAXDEG) col_slots[d1 * MAXDEG + p1] = s1;
    if (p2 < MAXDEG) col_slots[d2 * MAXDEG + p2] = s2;
    if (p3 < MAXDEG) col_slots[d3 * MAXDEG + p3] = s3;
}

// ---------------- standalone GEMM for layers 1,2 (fp16 in, A-direct) ----------------
__global__ __launch_bounds__(256) void gemm_mfma(const __half* __restrict__ Ah,
                                                 const __half* __restrict__ Wt,
                                                 __half* __restrict__ h16,
                                                 float* __restrict__ es,
                                                 float* __restrict__ ed) {
    __shared__ __half Bsw[144 * 128];   // 36 KB
    int tid = threadIdx.x;
    int brow = blockIdx.x * 64;
    int w = tid >> 6, l = tid & 63;
    int lrow = l & 15, lk = l >> 4;

    // --- A-direct fragment loads ---
    int arow = brow + w * 16 + lrow;
    half8 afr[4];
    if (arow < N_) {
        const char* rb = (const char*)(Ah + (size_t)arow * 128);
#pragma unroll
        for (int kk = 0; kk < 4; kk++)
            afr[kk] = *(const half8*)(rb + kk * 64 + lk * 16);
    } else {
#pragma unroll
        for (int kk = 0; kk < 4; kk++) afr[kk] = (half8)(_Float16)0.f;
    }

    // --- stage B ---
    {
        const float4* srcW = (const float4*)Wt;
#pragma unroll
        for (int i = 0; i < 9; i++) {
            int c = tid + i * 256;
            int o = c * 16;
            int n = o >> 8;
            float4 val = srcW[c];
            int addr = n * 256 + ((o & 255) ^ ((n & 7) << 4));
            *(float4*)((char*)Bsw + addr) = val;
        }
    }
    __syncthreads();

    f32x4 acc[9];
#pragma unroll
    for (int t = 0; t < 9; t++) acc[t] = (f32x4)0.f;
#pragma unroll
    for (int kk = 0; kk < 4; kk++) {
        int kbyte = kk * 64 + lk * 16;
#pragma unroll
        for (int t = 0; t < 9; t++) {
            int n = t * 16 + lrow;
            half8 bf = *(const half8*)((const char*)Bsw + n * 256 + (kbyte ^ ((n & 7) << 4)));
            acc[t] = __builtin_amdgcn_mfma_f32_16x16x32_f16(afr[kk], bf, acc[t], 0, 0, 0);
        }
    }

    int row0 = brow + w * 16 + lk * 4;
#pragma unroll
    for (int rr = 0; rr < 4; rr++) {
        int gr = row0 + rr;
        if (gr < N_) {
            half8 hv;
#pragma unroll
            for (int t = 0; t < 8; t++) hv[t] = (_Float16)acc[t][rr];
            *(half8*)(h16 + (size_t)gr * 128 + lrow * 8) = hv;
            if (lrow == 0) es[gr] = acc[8][rr];
            else if (lrow == 1) ed[gr] = acc[8][rr];
        }
    }
}

// ---------------- fused edge-softmax + gather-aggregate (one wave per dst node) ----------------
// FLAT-BATCH gather: 4 unconditional 16B gathers per batch (j = eg+16b+{0,4,8,12});
// lds_w = 0 beyond deg zeroes the overshoot; overshoot lanes point at the self row.
// UNNORMALIZED accumulation, z folded after the gather loop. No max pass (clamp 30).
__global__ __launch_bounds__(256) void gat_aggregate(const __half* __restrict__ h16,
                                                     const float* __restrict__ es,
                                                     const float* __restrict__ ed,
                                                     const int* __restrict__ cur,
                                                     const int* __restrict__ col_slots,
                                                     const float* __restrict__ biasp,
                                                     __half* __restrict__ hout) {
    __shared__ int   lds_s[4][64];
    __shared__ float lds_w[4][64];
    int wv = threadIdx.x >> 6;
    int lane = threadIdx.x & 63;
    int node = blockIdx.x * 4 + wv;
    if (node >= N_) return;

    // independent front loads
    int deg_raw = cur[node];
    int craw = col_slots[node * MAXDEG + lane];   // coalesced, unconditional
    float edn = ed[node];
    float es_self = es[node];

    int deg = min(deg_raw, MAXDEG);
    int c0 = (lane < deg) ? min(max(craw, 0), N_ - 1) : node;  // overshoot -> self row
    lds_s[wv][lane] = c0;

    float w0 = 0.f;
    if (lane < deg) w0 = __expf(fminf(leaky(es[c0] + edn), 30.f));
    float zl = w0;
    lds_w[wv][lane] = w0;

    int eg = lane >> 4;   // edge group 0..3
    int fl = lane & 15;   // 16-B slot: positions fl*8..fl*8+7

    float acc[8] = {0.f, 0.f, 0.f, 0.f, 0.f, 0.f, 0.f, 0.f};
    int K4 = (deg + 15) >> 4;   // flat batches (wave-uniform); deg=0 -> none
    for (int b = 0; b < K4; ++b) {
        int jb = eg + (b << 4);
        int s0 = lds_s[wv][jb];
        int s1 = lds_s[wv][jb + 4];
        int s2 = lds_s[wv][jb + 8];
        int s3 = lds_s[wv][jb + 12];
        float a0 = lds_w[wv][jb];
        float a1 = lds_w[wv][jb + 4];
        float a2 = lds_w[wv][jb + 8];
        float a3 = lds_w[wv][jb + 12];
        union { float4 f4; __half2 h2[4]; } u0, u1, u2, u3;
        u0.f4 = *(const float4*)(h16 + (size_t)s0 * 128 + fl * 8);
        u1.f4 = *(const float4*)(h16 + (size_t)s1 * 128 + fl * 8);
        u2.f4 = *(const float4*)(h16 + (size_t)s2 * 128 + fl * 8);
        u3.f4 = *(const float4*)(h16 + (size_t)s3 * 128 + fl * 8);
#pragma unroll
        for (int qq = 0; qq < 4; qq++) {
            float2 f0 = __half22float2(u0.h2[qq]);
            float2 f1 = __half22float2(u1.h2[qq]);
            float2 f2 = __half22float2(u2.h2[qq]);
            float2 f3 = __half22float2(u3.h2[qq]);
            acc[2 * qq]     += a0 * f0.x + a1 * f1.x + a2 * f2.x + a3 * f3.x;
            acc[2 * qq + 1] += a0 * f0.y + a1 * f1.y + a2 * f2.y + a3 * f3.y;
        }
    }

    // fold the 4 edge groups, then z (off the load path)
#pragma unroll
    for (int qq = 0; qq < 8; qq++) {
        acc[qq] += __shfl_xor(acc[qq], 16);
        acc[qq] += __shfl_xor(acc[qq], 32);
    }
#pragma unroll
    for (int o = 32; o; o >>= 1) zl += __shfl_xor(zl, o);
    float ws = __expf(fminf(leaky(es_self + edn), 30.f));  // self-loop
    float inv = 1.0f / (zl + ws + 1e-16f);

    if (eg == 0) {
        union { float4 f4; __half2 h2[4]; } su;
        su.f4 = *(const float4*)(h16 + (size_t)node * 128 + fl * 8);
        const float4* bp = (const float4*)(biasp + fl * 8);
        float4 b0 = bp[0], b1 = bp[1];
        float bq[8] = {b0.x, b0.y, b0.z, b0.w, b1.x, b1.y, b1.z, b1.w};
        union { float4 f4; __half2 h2[4]; } ou;
#pragma unroll
        for (int qq = 0; qq < 4; qq++) {
            float2 sv = __half22float2(su.h2[qq]);
            float v0 = fmaxf((acc[2 * qq]     + ws * sv.x) * inv + bq[2 * qq],     0.f);
            float v1 = fmaxf((acc[2 * qq + 1] + ws * sv.y) * inv + bq[2 * qq + 1], 0.f);
            ou.h2[qq] = __floats2half2_rn(v0, v1);
        }
        *(float4*)(hout + (size_t)node * 128 + fl * 8) = ou.f4;
    }
}

// ---------------- fused global max pool + MLP head + log_softmax ----------------
__device__ __forceinline__ int lower_bound_batch(const int* __restrict__ batch, int val) {
    int lo = 0, hi = N_;
    while (lo < hi) {
        int mid = (lo + hi) >> 1;
        if (batch[mid] < val) lo = mid + 1;
        else hi = mid;
    }
    return lo;
}

__global__ __launch_bounds__(512) void pool_head(const __half* __restrict__ h16,
                                                 const int* __restrict__ batch,
                                                 const float* __restrict__ W1,
                                                 const float* __restrict__ b1,
                                                 const float* __restrict__ W2,
                                                 const float* __restrict__ b2,
                                                 float* __restrict__ out) {
    int g = blockIdx.x;
    int t = threadIdx.x;
    __shared__ float red[8][128];
    __shared__ float gs[128], gp[128], lg[C_], lse;

    int s = lower_bound_batch(batch, g);
    int e = lower_bound_batch(batch, g + 1);
    int fs = t & 15;
    int rg = t >> 4;
    float m[8] = {0.f, 0.f, 0.f, 0.f, 0.f, 0.f, 0.f, 0.f};
    for (int i = s + rg; i < e; i += 32) {
        union { float4 f4; __half2 h2[4]; } u;
        u.f4 = *(const float4*)(h16 + (size_t)i * 128 + fs * 8);
#pragma unroll
        for (int qq = 0; qq < 4; qq++) {
            float2 fv = __half22float2(u.h2[qq]);
            m[2 * qq]     = fmaxf(m[2 * qq],     fv.x);
            m[2 * qq + 1] = fmaxf(m[2 * qq + 1], fv.y);
        }
    }
#pragma unroll
    for (int qq = 0; qq < 8; qq++) {
        m[qq] = fmaxf(m[qq], __shfl_xor(m[qq], 16));
        m[qq] = fmaxf(m[qq], __shfl_xor(m[qq], 32));
    }
    int wid = t >> 6;
    if ((t & 48) == 0) {
#pragma unroll
        for (int qq = 0; qq < 8; qq++) red[wid][fs * 8 + qq] = m[qq];
    }
    __syncthreads();
    if (t < 128) {
        float mm = red[0][t];
#pragma unroll
        for (int w = 1; w < 8; w++) mm = fmaxf(mm, red[w][t]);
        gs[t] = mm;
    }
    __syncthreads();

    if (t < 128) {
        float acc = b1[t];
#pragma unroll 8
        for (int k = 0; k < 128; k++) {
            int f = pi_out(k);
            acc += gs[k] * W1[f * 128 + t];
        }
        gp[t] = fmaxf(acc, 0.f);
    }
    __syncthreads();
    if (t < C_) {
        float a2 = b2[t];
#pragma unroll 8
        for (int k = 0; k < 128; k++) a2 += gp[k] * W2[k * C_ + t];
        lg[t] = a2;
    }
    __syncthreads();
    if (t == 0) {
        float mm = lg[0];
#pragma unroll
        for (int i = 1; i < C_; i++) mm = fmaxf(mm, lg[i]);
        float ss = 0.f;
#pragma unroll
        for (int i = 0; i < C_; i++) ss += expf(lg[i] - mm);
        lse = mm + logf(ss);
    }
    __syncthreads();
    if (t < C_) out[g * C_ + t] = lg[t] - lse;
}

// ---------------- launch ----------------
extern "C" void kernel_launch(void* const* d_in, const int* in_sizes, int n_in,
                              void* d_out, int out_size, void* d_ws, size_t ws_size,
                              hipStream_t stream) {
    const float* x     = (const float*)d_in[0];
    const int*   eidx  = (const int*)d_in[1];
    const int*   batch = (const int*)d_in[2];
    const float* Wc    = (const float*)d_in[3];
    const float* a_src = (const float*)d_in[4];
    const float* a_dst = (const float*)d_in[5];
    const float* bc    = (const float*)d_in[6];
    const float* W1    = (const float*)d_in[7];
    const float* b1    = (const float*)d_in[8];
    const float* W2    = (const float*)d_in[9];
    const float* b2    = (const float*)d_in[10];
    float* out = (float*)d_out;

    const int* srcs = eidx;        // edge_index[0]
    const int* dsts = eidx + E_;   // edge_index[1]

    // workspace layout (16B-aligned segments)
    __half* hG16  = (__half*)d_ws;                      // [N][128] gemm out (permuted)
    __half* hB16  = hG16 + (size_t)N_ * 128;            // [N][128] aggregate out
    float*  es    = (float*)(hB16 + (size_t)N_ * 128);  // N
    float*  ed    = es + N_;                            // N
    float*  bcp   = ed + N_;                            // 3*128
    __half* Wt    = (__half*)(bcp + 3 * 128);           // 3*144*128
    int*    cur       = (int*)(Wt + (size_t)3 * 144 * 128); // N
    int*    col_slots = cur + N_;                           // MAXDEG*N

    // ---- kernel 1: prep all weights + zero cursors ----
    zero_prep<<<L_ + (N_ + 255) / 256, 256, 0, stream>>>(cur, Wc, a_src, a_dst, bc, Wt, bcp);

    // ---- kernel 2: GEMM layer 0 (A-direct) with embedded slot-fill ----
    gemm0_fill<<<GEMM_BLKS, 256, 0, stream>>>(x, Wt, hG16, es, ed,
                                              srcs, dsts, cur, col_slots);

    // ---- layers ----
    gat_aggregate<<<ABLK, 256, 0, stream>>>(hG16, es, ed, cur, col_slots, bcp, hB16);
    for (int l = 1; l < L_; ++l) {
        gemm_mfma<<<GEMM_BLKS, 256, 0, stream>>>(
            hB16, Wt + (size_t)l * 144 * 128, hG16, es, ed);
        gat_aggregate<<<ABLK, 256, 0, stream>>>(hG16, es, ed, cur, col_slots,
                                                bcp + l * 128, hB16);
    }

    // ---- fused pool + head ----
    pool_head<<<G_, 512, 0, stream>>>(hB16, batch, W1, b1, W2, b2, out);
}